// Round 1
// baseline (69.774 us; speedup 1.0000x reference)
//
#include <hip/hip_runtime.h>

// Problem constants (from reference): B=4, C=128, H=64, W=64, L=16, K=64, CD=8.
// C == L*CD. HW = H*W = 4096.
#define Bn   4
#define Cn   128
#define HWn  4096
#define Ln   16
#define Kn   64
#define CDn  8
#define QUANT_ELEMS (Bn * Cn * HWn)   // 2,097,152

typedef float floatx8 __attribute__((ext_vector_type(8)));
typedef float floatx4 __attribute__((ext_vector_type(4)));

// One thread = one (b, l, pixel) slot.
// Key change vs previous version: the 64x8 code table for this block's l is
// read through WAVE-UNIFORM global loads (s_load / K$-resident scalar path)
// instead of LDS broadcasts. The previous kernel issued 128 ds_read_b128
// broadcasts per wave in the k-loop (~12 cyc each on the per-CU LDS pipe,
// shared by 16 waves => ~10 µs of pure LDS serialization + lgkmcnt stalls).
// Codes are 2 KB per l: fully resident in the scalar cache; FMAs take the
// code operand directly from SGPRs (1 SGPR src per VALU instr is legal).
// Distance arithmetic is bit-identical to the passing kernel (sub + fmaf,
// ascending d, strict < keeps lowest k) so argmin decisions cannot flip.
__global__ __launch_bounds__(256)
void soft_to_hard_encoder_kernel(const float* __restrict__ z,
                                 const float* __restrict__ codes,
                                 float* __restrict__ out) {
    // blockIdx.x = ((b*Ln + l) * 16) + pixblock ; 16 blocks of 256 pix per (b,l)
    const int pixblock = blockIdx.x & 15;
    const int bl       = blockIdx.x >> 4;
    const int l        = bl & (Ln - 1);
    const int b        = bl >> 4;
    const int pix      = pixblock * 256 + threadIdx.x;

    // Wave-uniform base pointer to this latent slot's codes (64 x 8 floats, 2 KB).
    const float* __restrict__ cl = codes + (size_t)l * (Kn * CDn);

    // Load this slot's 8-dim latent vector. Channel c = l*8 + d; address
    // ((b*Cn + c) * HWn + pix) is consecutive across lanes -> coalesced 256B/instr.
    float hz[CDn];
    #pragma unroll
    for (int d = 0; d < CDn; ++d)
        hz[d] = z[(size_t)(b * Cn + l * CDn + d) * HWn + pix];

    // Argmin over 64 codes; strict < keeps the first (lowest k) on ties,
    // matching np.argmin semantics. Code vectors arrive via uniform 32B loads
    // (scalar path); unroll 8 keeps ~4 x s_load_dwordx16 worth in flight.
    float best = 3.402823466e+38f;
    int bidx = 0;
    #pragma unroll 8
    for (int k = 0; k < Kn; ++k) {
        floatx8 c = *(const floatx8*)(cl + k * CDn);  // uniform -> SMEM/K$
        float s = 0.0f;
        #pragma unroll
        for (int d = 0; d < CDn; ++d) {
            float df = hz[d] - c[d];
            s = fmaf(df, df, s);
        }
        if (s < best) { best = s; bidx = k; }
    }

    // Winner-code gather: per-lane bidx -> two dwordx4 L1 hits (codes resident).
    const floatx4 w0 = *(const floatx4*)(cl + bidx * CDn);
    const floatx4 w1 = *(const floatx4*)(cl + bidx * CDn + 4);

    // Hard symbols back to NCHW (coalesced per d).
    #pragma unroll
    for (int d = 0; d < 4; ++d) {
        out[(size_t)(b * Cn + l * CDn + d)     * HWn + pix] = w0[d];
        out[(size_t)(b * Cn + l * CDn + 4 + d) * HWn + pix] = w1[d];
    }

    // idxes layout (b,h,w,l): offset after the quantized block; stored as float.
    // Stride-16 scatter: 4B per 64B sector, but the 1 MiB region lives in L2
    // during the kernel so lines merge before HBM writeback — negligible cost.
    out[QUANT_ELEMS + (size_t)(b * HWn + pix) * Ln + l] = (float)bidx;
}

extern "C" void kernel_launch(void* const* d_in, const int* in_sizes, int n_in,
                              void* d_out, int out_size, void* d_ws, size_t ws_size,
                              hipStream_t stream) {
    const float* z     = (const float*)d_in[0];  // (4,128,64,64) fp32
    const float* codes = (const float*)d_in[1];  // (16,64,8) fp32
    float* out         = (float*)d_out;          // quantized (2,097,152) + idxes (262,144)

    const int total_threads = Bn * Ln * HWn;     // 262,144
    const int blocks = total_threads / 256;      // 1024
    soft_to_hard_encoder_kernel<<<blocks, 256, 0, stream>>>(z, codes, out);
}